// Round 1
// baseline (500.627 us; speedup 1.0000x reference)
//
#include <hip/hip_runtime.h>

#define N_NODES 20000
#define FDIM 512
#define SSZ 6

// ---------------------------------------------------------------------------
// K1: dual GEMM  y_re = x@W_re + b_re,  y_im = x@W_im + b_im
// 64x64 tile, 16 k-slice, 256 threads, each thread 4x4 outputs for re and im.
// A stored transposed in LDS ([k][row]) so fragment reads are float4.
// ---------------------------------------------------------------------------
__global__ __launch_bounds__(256) void gemm_dual(
    const float* __restrict__ x,
    const float* __restrict__ Wre,
    const float* __restrict__ Wim,
    const float* __restrict__ bre,
    const float* __restrict__ bim,
    float* __restrict__ yre,
    float* __restrict__ yim)
{
    __shared__ __align__(16) float As [16][68];   // [k][row], pad 68 (272B, 16B-aligned rows)
    __shared__ __align__(16) float Bre[16][68];   // [k][col]
    __shared__ __align__(16) float Bim[16][68];

    const int tid = threadIdx.x;
    const int tx = tid & 15, ty = tid >> 4;
    const int rowBase = blockIdx.y * 64;
    const int colBase = blockIdx.x * 64;

    float accR[4][4] = {{0.f}}, accI[4][4] = {{0.f}};

    const int ar = tid >> 2;          // 0..63 (row within tile)
    const int aq = (tid & 3) << 2;    // 0,4,8,12 (k within slice)
    const int bk = tid >> 4;          // 0..15 (k)
    const int bc = (tid & 15) << 2;   // 0..60 (col)

    for (int k0 = 0; k0 < FDIM; k0 += 16) {
        const int row = rowBase + ar;
        float4 av = make_float4(0.f, 0.f, 0.f, 0.f);
        if (row < N_NODES) av = *(const float4*)(x + (size_t)row * FDIM + k0 + aq);
        As[aq + 0][ar] = av.x;
        As[aq + 1][ar] = av.y;
        As[aq + 2][ar] = av.z;
        As[aq + 3][ar] = av.w;
        const float4 brv = *(const float4*)(Wre + (size_t)(k0 + bk) * FDIM + colBase + bc);
        const float4 biv = *(const float4*)(Wim + (size_t)(k0 + bk) * FDIM + colBase + bc);
        *(float4*)(&Bre[bk][bc]) = brv;
        *(float4*)(&Bim[bk][bc]) = biv;
        __syncthreads();
#pragma unroll
        for (int kk = 0; kk < 16; ++kk) {
            const float4 a4  = *(const float4*)(&As [kk][ty << 2]);
            const float4 b4r = *(const float4*)(&Bre[kk][tx << 2]);
            const float4 b4i = *(const float4*)(&Bim[kk][tx << 2]);
            const float a[4]  = {a4.x, a4.y, a4.z, a4.w};
            const float br_[4] = {b4r.x, b4r.y, b4r.z, b4r.w};
            const float bi_[4] = {b4i.x, b4i.y, b4i.z, b4i.w};
#pragma unroll
            for (int i = 0; i < 4; ++i)
#pragma unroll
                for (int j = 0; j < 4; ++j) {
                    accR[i][j] = fmaf(a[i], br_[j], accR[i][j]);
                    accI[i][j] = fmaf(a[i], bi_[j], accI[i][j]);
                }
        }
        __syncthreads();
    }

    const int col = colBase + (tx << 2);
    const float4 bre4 = *(const float4*)(bre + col);
    const float4 bim4 = *(const float4*)(bim + col);
#pragma unroll
    for (int i = 0; i < 4; ++i) {
        const int row = rowBase + (ty << 2) + i;
        if (row < N_NODES) {
            float4 vr = make_float4(accR[i][0] + bre4.x, accR[i][1] + bre4.y,
                                    accR[i][2] + bre4.z, accR[i][3] + bre4.w);
            float4 vi = make_float4(accI[i][0] + bim4.x, accI[i][1] + bim4.y,
                                    accI[i][2] + bim4.z, accI[i][3] + bim4.w);
            *(float4*)(yre + (size_t)row * FDIM + col) = vr;
            *(float4*)(yim + (size_t)row * FDIM + col) = vi;
        }
    }
}

// ---------------------------------------------------------------------------
// K2: per-node unitary row (truncated exp series of -0.025i*L, row 0),
// gather y over subgraph, complex combine, ReLU -> write straight into d_out.
// out layout: [N, 1024] = [re(512) | im(512)]
// ---------------------------------------------------------------------------
__global__ __launch_bounds__(128) void evolve_relu(
    const float* __restrict__ yre,
    const float* __restrict__ yim,
    const int* __restrict__ sub_nodes,
    const int* __restrict__ sub_adj,
    float* __restrict__ out)
{
    __shared__ float rre[SSZ], rim[SSZ];
    __shared__ int nodes[SSZ];
    const int n = blockIdx.x;
    const int tid = threadIdx.x;

    if (tid < SSZ) nodes[tid] = sub_nodes[n * SSZ + tid];
    if (tid == 0) {
        const int* sa = sub_adj + (size_t)n * SSZ * SSZ;
        float A[SSZ][SSZ], deg[SSZ];
#pragma unroll
        for (int s = 0; s < SSZ; ++s) {
            float d = 0.f;
#pragma unroll
            for (int t = 0; t < SSZ; ++t) { float a = (float)sa[s * SSZ + t]; A[s][t] = a; d += a; }
            deg[s] = d;
        }
        float p1[SSZ], p2[SSZ], p3[SSZ], p4[SSZ];
#pragma unroll
        for (int t = 0; t < SSZ; ++t) p1[t] = ((t == 0) ? deg[0] : 0.f) - A[0][t];
        // row-vector * L steps
#pragma unroll
        for (int t = 0; t < SSZ; ++t) {
            float acc = 0.f;
#pragma unroll
            for (int s = 0; s < SSZ; ++s) acc += p1[s] * (((s == t) ? deg[s] : 0.f) - A[s][t]);
            p2[t] = acc;
        }
#pragma unroll
        for (int t = 0; t < SSZ; ++t) {
            float acc = 0.f;
#pragma unroll
            for (int s = 0; s < SSZ; ++s) acc += p2[s] * (((s == t) ? deg[s] : 0.f) - A[s][t]);
            p3[t] = acc;
        }
#pragma unroll
        for (int t = 0; t < SSZ; ++t) {
            float acc = 0.f;
#pragma unroll
            for (int s = 0; s < SSZ; ++s) acc += p3[s] * (((s == t) ? deg[s] : 0.f) - A[s][t]);
            p4[t] = acc;
        }
        // series coefficients of (-0.025i)^k / k!
#pragma unroll
        for (int t = 0; t < SSZ; ++t) {
            rre[t] = ((t == 0) ? 1.f : 0.f) - 3.125e-4f * p2[t] + 1.6276041666666668e-8f * p4[t];
            rim[t] = -0.025f * p1[t] + 2.6041666666666666e-6f * p3[t];
        }
    }
    __syncthreads();

    const int f = tid << 2;   // 128 threads x 4 features = 512
    float4 aR = make_float4(0.f, 0.f, 0.f, 0.f);
    float4 aI = make_float4(0.f, 0.f, 0.f, 0.f);
#pragma unroll
    for (int s = 0; s < SSZ; ++s) {
        const float cr = rre[s], ci = rim[s];
        const size_t base = (size_t)nodes[s] * FDIM + f;
        const float4 yr = *(const float4*)(yre + base);
        const float4 yi = *(const float4*)(yim + base);
        aR.x += cr * yr.x - ci * yi.x;  aI.x += cr * yi.x + ci * yr.x;
        aR.y += cr * yr.y - ci * yi.y;  aI.y += cr * yi.y + ci * yr.y;
        aR.z += cr * yr.z - ci * yi.z;  aI.z += cr * yi.z + ci * yr.z;
        aR.w += cr * yr.w - ci * yi.w;  aI.w += cr * yi.w + ci * yr.w;
    }
    float4 er = make_float4(fmaxf(aR.x, 0.f), fmaxf(aR.y, 0.f), fmaxf(aR.z, 0.f), fmaxf(aR.w, 0.f));
    float4 ei = make_float4(fmaxf(aI.x, 0.f), fmaxf(aI.y, 0.f), fmaxf(aI.z, 0.f), fmaxf(aI.w, 0.f));
    *(float4*)(out + (size_t)n * 1024 + f) = er;
    *(float4*)(out + (size_t)n * 1024 + 512 + f) = ei;
}

// ---------------------------------------------------------------------------
// K3: per-feature sum / sumsq of er, ei (reads d_out), atomics into sums[2048]
// ---------------------------------------------------------------------------
__global__ __launch_bounds__(512) void stats_kernel(
    const float* __restrict__ out, float* __restrict__ sums)
{
    const int tid = threadIdx.x;          // feature 0..511
    const int r0 = blockIdx.x * 40;       // 500 blocks x 40 rows
    float sr = 0.f, sr2 = 0.f, si = 0.f, si2 = 0.f;
    for (int r = r0; r < r0 + 40; ++r) {
        const float vr = out[(size_t)r * 1024 + tid];
        const float vi = out[(size_t)r * 1024 + 512 + tid];
        sr += vr; sr2 = fmaf(vr, vr, sr2);
        si += vi; si2 = fmaf(vi, vi, si2);
    }
    atomicAdd(&sums[tid], sr);
    atomicAdd(&sums[512 + tid], sr2);
    atomicAdd(&sums[1024 + tid], si);
    atomicAdd(&sums[1536 + tid], si2);
}

// ---------------------------------------------------------------------------
// K3b: fold BN stats into per-feature scale/shift
// ---------------------------------------------------------------------------
__global__ __launch_bounds__(512) void bnparams_kernel(
    const float* __restrict__ sums,
    const float* __restrict__ gr, const float* __restrict__ br_,
    const float* __restrict__ gi, const float* __restrict__ bi_,
    float* __restrict__ prm)
{
    const int f = threadIdx.x;
    const float invN = 1.0f / (float)N_NODES;
    const float mur = sums[f] * invN;
    const float varr = fmaf(-mur, mur, sums[512 + f] * invN);
    const float scr = rsqrtf(varr + 1e-5f) * gr[f];
    prm[f] = scr;
    prm[512 + f] = fmaf(-mur, scr, br_[f]);
    const float mui = sums[1024 + f] * invN;
    const float vari = fmaf(-mui, mui, sums[1536 + f] * invN);
    const float sci = rsqrtf(vari + 1e-5f) * gi[f];
    prm[1024 + f] = sci;
    prm[1536 + f] = fmaf(-mui, sci, bi_[f]);
}

// ---------------------------------------------------------------------------
// K4: in-place BN apply + residual on real half
// ---------------------------------------------------------------------------
__global__ __launch_bounds__(256) void finalize_kernel(
    const float* __restrict__ x, const float* __restrict__ prm,
    float* __restrict__ out)
{
    const int gid = blockIdx.x * 256 + threadIdx.x;   // N*128 threads
    const int n = gid >> 7;
    const int f = (gid & 127) << 2;
    float4 er = *(const float4*)(out + (size_t)n * 1024 + f);
    float4 ei = *(const float4*)(out + (size_t)n * 1024 + 512 + f);
    const float4 xv  = *(const float4*)(x + (size_t)n * FDIM + f);
    const float4 scr = *(const float4*)(prm + f);
    const float4 shr = *(const float4*)(prm + 512 + f);
    const float4 sci = *(const float4*)(prm + 1024 + f);
    const float4 shi = *(const float4*)(prm + 1536 + f);
    float4 orr, oii;
    orr.x = fmaf(er.x, scr.x, shr.x) + xv.x;
    orr.y = fmaf(er.y, scr.y, shr.y) + xv.y;
    orr.z = fmaf(er.z, scr.z, shr.z) + xv.z;
    orr.w = fmaf(er.w, scr.w, shr.w) + xv.w;
    oii.x = fmaf(ei.x, sci.x, shi.x);
    oii.y = fmaf(ei.y, sci.y, shi.y);
    oii.z = fmaf(ei.z, sci.z, shi.z);
    oii.w = fmaf(ei.w, sci.w, shi.w);
    *(float4*)(out + (size_t)n * 1024 + f) = orr;
    *(float4*)(out + (size_t)n * 1024 + 512 + f) = oii;
}

extern "C" void kernel_launch(void* const* d_in, const int* in_sizes, int n_in,
                              void* d_out, int out_size, void* d_ws, size_t ws_size,
                              hipStream_t stream)
{
    const float* x        = (const float*)d_in[0];
    // d_in[1] = edge_index (unused: sub_nodes/sub_adj are precomputed)
    const int* sub_nodes  = (const int*)d_in[2];
    const int* sub_adj    = (const int*)d_in[3];
    const float* Wre      = (const float*)d_in[4];
    const float* Wim      = (const float*)d_in[5];
    const float* bre      = (const float*)d_in[6];
    const float* bim      = (const float*)d_in[7];
    const float* gr       = (const float*)d_in[8];
    const float* br_      = (const float*)d_in[9];
    const float* gi       = (const float*)d_in[10];
    const float* bi_      = (const float*)d_in[11];
    float* out = (float*)d_out;

    float* yre  = (float*)d_ws;                       // N*F
    float* yim  = yre + (size_t)N_NODES * FDIM;       // N*F
    float* sums = yim + (size_t)N_NODES * FDIM;       // 2048
    float* prm  = sums + 2048;                        // 2048

    hipMemsetAsync(sums, 0, 2048 * sizeof(float), stream);

    dim3 g1(FDIM / 64, (N_NODES + 63) / 64);
    gemm_dual<<<g1, 256, 0, stream>>>(x, Wre, Wim, bre, bim, yre, yim);
    evolve_relu<<<N_NODES, 128, 0, stream>>>(yre, yim, sub_nodes, sub_adj, out);
    stats_kernel<<<500, 512, 0, stream>>>(out, sums);
    bnparams_kernel<<<1, 512, 0, stream>>>(sums, gr, br_, gi, bi_, prm);
    finalize_kernel<<<(N_NODES * 128) / 256, 256, 0, stream>>>(x, prm, out);
}

// Round 2
// 315.399 us; speedup vs baseline: 1.5873x; 1.5873x over previous
//
#include <hip/hip_runtime.h>

#define N_NODES 20000
#define FDIM 512
#define SSZ 6

typedef __attribute__((ext_vector_type(8))) short bf16x8;
typedef __attribute__((ext_vector_type(4))) float f32x4;
typedef __attribute__((ext_vector_type(8))) unsigned short u16x8;

static __device__ __forceinline__ unsigned short f2bf(float f) {
    unsigned int u = __float_as_uint(f);
    unsigned int r = (u + 0x7fffu + ((u >> 16) & 1u)) >> 16;
    return (unsigned short)r;
}

// ---------------------------------------------------------------------------
// K0a: x fp32 -> bf16 (same layout). 20000*512 elems, 8 per thread.
// ---------------------------------------------------------------------------
__global__ __launch_bounds__(256) void conv_x(
    const float* __restrict__ x, unsigned short* __restrict__ xb)
{
    const size_t i = ((size_t)blockIdx.x * 256 + threadIdx.x) * 8;
    const float4 a = *(const float4*)(x + i);
    const float4 b = *(const float4*)(x + i + 4);
    u16x8 o;
    o[0] = f2bf(a.x); o[1] = f2bf(a.y); o[2] = f2bf(a.z); o[3] = f2bf(a.w);
    o[4] = f2bf(b.x); o[5] = f2bf(b.y); o[6] = f2bf(b.z); o[7] = f2bf(b.w);
    *(u16x8*)(xb + i) = o;
}

// ---------------------------------------------------------------------------
// K0b: build B^T bf16: wt[n][k] = Wre[k][n] (n<512) | Wim[k][n-512]
// LDS 32x33 tile transpose. grid (16,16,2), block (32,8).
// ---------------------------------------------------------------------------
__global__ __launch_bounds__(256) void conv_wt(
    const float* __restrict__ Wre, const float* __restrict__ Wim,
    unsigned short* __restrict__ wt)
{
    __shared__ float tile[32][33];
    const float* W = blockIdx.z ? Wim : Wre;
    const int tx = threadIdx.x, ty = threadIdx.y;
    const int k0 = blockIdx.x * 32;
    const int n0 = blockIdx.y * 32;
#pragma unroll
    for (int i = 0; i < 4; ++i)
        tile[ty + i * 8][tx] = W[(size_t)(k0 + ty + i * 8) * FDIM + n0 + tx];
    __syncthreads();
    unsigned short* wtb = wt + (size_t)blockIdx.z * FDIM * FDIM;
#pragma unroll
    for (int i = 0; i < 4; ++i)
        wtb[(size_t)(n0 + ty + i * 8) * FDIM + k0 + tx] = f2bf(tile[tx][ty + i * 8]);
}

// ---------------------------------------------------------------------------
// K1: bf16 MFMA GEMM.  y[M=20000][1024] = xb[M][512] @ wt^T + bias
// 128x128 tile, BK=64, 4 waves (2x2), each wave 4x4 frags of 16x16x32.
// global_load_lds width=16 staging; XOR chunk swizzle (slot = g ^ (row&7))
// so ds_read_b128 fragment reads land 2-way (free) instead of 16-way.
// ---------------------------------------------------------------------------
#define BM 128
#define BN 128
#define BK 64

__global__ __launch_bounds__(256) void gemm_mfma(
    const unsigned short* __restrict__ xb,   // [20000][512] bf16
    const unsigned short* __restrict__ wt,   // [1024][512] bf16
    const float* __restrict__ bre, const float* __restrict__ bim,
    float* __restrict__ y)                   // [20000][1024]
{
    __shared__ __align__(16) unsigned short lA[BM * BK];   // 16 KB
    __shared__ __align__(16) unsigned short lB[BN * BK];   // 16 KB

    const int tid  = threadIdx.x;
    const int wave = tid >> 6;
    const int lane = tid & 63;
    const int rowBase = blockIdx.y * BM;
    const int colBase = blockIdx.x * BN;

    const int wm = (wave >> 1) * 64;
    const int wn = (wave & 1) * 64;

    f32x4 acc[4][4];
#pragma unroll
    for (int i = 0; i < 4; ++i)
#pragma unroll
        for (int j = 0; j < 4; ++j) acc[i][j] = (f32x4){0.f, 0.f, 0.f, 0.f};

    // staging roles: 8 lanes per row (8 x 16B = one 64-elem bf16 row), 8 rows/inst
    const int srow   = lane >> 3;            // 0..7
    const int schunk = lane & 7;             // LDS slot chunk
    const int gchunk = schunk ^ srow;        // global chunk to fetch (row&7 == srow)
    const int aRow0  = wave * 32;            // this wave stages rows [aRow0, aRow0+32)

    const int fm = lane & 15;                // m/n within 16
    const int kq = lane >> 4;                // k-quad 0..3

    for (int k0 = 0; k0 < FDIM; k0 += BK) {
        // ---- stage A: 4 insts/wave, 8 rows each ----
#pragma unroll
        for (int i = 0; i < 4; ++i) {
            const int trow = aRow0 + i * 8;                    // multiple of 8
            int grow = rowBase + trow + srow;
            if (grow > N_NODES - 1) grow = N_NODES - 1;
            const unsigned short* gp = xb + (size_t)grow * FDIM + k0 + gchunk * 8;
            __builtin_amdgcn_global_load_lds(
                (const __attribute__((address_space(1))) void*)gp,
                (__attribute__((address_space(3))) void*)(lA + trow * BK), 16, 0, 0);
        }
        // ---- stage B ----
#pragma unroll
        for (int i = 0; i < 4; ++i) {
            const int trow = aRow0 + i * 8;
            const int grow = colBase + trow + srow;            // < 1024 always
            const unsigned short* gp = wt + (size_t)grow * FDIM + k0 + gchunk * 8;
            __builtin_amdgcn_global_load_lds(
                (const __attribute__((address_space(1))) void*)gp,
                (__attribute__((address_space(3))) void*)(lB + trow * BK), 16, 0, 0);
        }
        __syncthreads();

#pragma unroll
        for (int ks = 0; ks < 2; ++ks) {
            bf16x8 af[4], bfr[4];
            const int g = ks * 4 + kq;       // linear chunk 0..7
#pragma unroll
            for (int mt = 0; mt < 4; ++mt) {
                const int row = wm + mt * 16 + fm;
                af[mt] = *(const bf16x8*)&lA[row * BK + ((g ^ (row & 7)) << 3)];
            }
#pragma unroll
            for (int nt = 0; nt < 4; ++nt) {
                const int row = wn + nt * 16 + fm;
                bfr[nt] = *(const bf16x8*)&lB[row * BK + ((g ^ (row & 7)) << 3)];
            }
#pragma unroll
            for (int mt = 0; mt < 4; ++mt)
#pragma unroll
                for (int nt = 0; nt < 4; ++nt)
                    acc[mt][nt] = __builtin_amdgcn_mfma_f32_16x16x32_bf16(
                        af[mt], bfr[nt], acc[mt][nt], 0, 0, 0);
        }
        __syncthreads();
    }

    // ---- epilogue: C/D layout col=lane&15, row=(lane>>4)*4+r ----
    const int rquad = lane >> 4;
#pragma unroll
    for (int nt = 0; nt < 4; ++nt) {
        const int col = colBase + wn + nt * 16 + fm;
        const float bias = (col < FDIM) ? bre[col] : bim[col - FDIM];
#pragma unroll
        for (int mt = 0; mt < 4; ++mt) {
            const int row0 = rowBase + wm + mt * 16 + rquad * 4;
#pragma unroll
            for (int r = 0; r < 4; ++r) {
                const int row = row0 + r;
                if (row < N_NODES)
                    y[(size_t)row * 1024 + col] = acc[mt][nt][r] + bias;
            }
        }
    }
}

// ---------------------------------------------------------------------------
// K2: per-node unitary row, gather y, complex combine, ReLU -> d_out
// y layout: [n][1024] = re(512) | im(512)
// ---------------------------------------------------------------------------
__global__ __launch_bounds__(128) void evolve_relu(
    const float* __restrict__ y,
    const int* __restrict__ sub_nodes,
    const int* __restrict__ sub_adj,
    float* __restrict__ out)
{
    __shared__ float rre[SSZ], rim[SSZ];
    __shared__ int nodes[SSZ];
    const int n = blockIdx.x;
    const int tid = threadIdx.x;

    if (tid < SSZ) nodes[tid] = sub_nodes[n * SSZ + tid];
    if (tid == 0) {
        const int* sa = sub_adj + (size_t)n * SSZ * SSZ;
        float A[SSZ][SSZ], deg[SSZ];
#pragma unroll
        for (int s = 0; s < SSZ; ++s) {
            float d = 0.f;
#pragma unroll
            for (int t = 0; t < SSZ; ++t) { float a = (float)sa[s * SSZ + t]; A[s][t] = a; d += a; }
            deg[s] = d;
        }
        float p1[SSZ], p2[SSZ], p3[SSZ], p4[SSZ];
#pragma unroll
        for (int t = 0; t < SSZ; ++t) p1[t] = ((t == 0) ? deg[0] : 0.f) - A[0][t];
#pragma unroll
        for (int t = 0; t < SSZ; ++t) {
            float acc = 0.f;
#pragma unroll
            for (int s = 0; s < SSZ; ++s) acc += p1[s] * (((s == t) ? deg[s] : 0.f) - A[s][t]);
            p2[t] = acc;
        }
#pragma unroll
        for (int t = 0; t < SSZ; ++t) {
            float acc = 0.f;
#pragma unroll
            for (int s = 0; s < SSZ; ++s) acc += p2[s] * (((s == t) ? deg[s] : 0.f) - A[s][t]);
            p3[t] = acc;
        }
#pragma unroll
        for (int t = 0; t < SSZ; ++t) {
            float acc = 0.f;
#pragma unroll
            for (int s = 0; s < SSZ; ++s) acc += p3[s] * (((s == t) ? deg[s] : 0.f) - A[s][t]);
            p4[t] = acc;
        }
#pragma unroll
        for (int t = 0; t < SSZ; ++t) {
            rre[t] = ((t == 0) ? 1.f : 0.f) - 3.125e-4f * p2[t] + 1.6276041666666668e-8f * p4[t];
            rim[t] = -0.025f * p1[t] + 2.6041666666666666e-6f * p3[t];
        }
    }
    __syncthreads();

    const int f = tid << 2;
    float4 aR = make_float4(0.f, 0.f, 0.f, 0.f);
    float4 aI = make_float4(0.f, 0.f, 0.f, 0.f);
#pragma unroll
    for (int s = 0; s < SSZ; ++s) {
        const float cr = rre[s], ci = rim[s];
        const size_t base = (size_t)nodes[s] * 1024 + f;
        const float4 yr = *(const float4*)(y + base);
        const float4 yi = *(const float4*)(y + base + FDIM);
        aR.x += cr * yr.x - ci * yi.x;  aI.x += cr * yi.x + ci * yr.x;
        aR.y += cr * yr.y - ci * yi.y;  aI.y += cr * yi.y + ci * yr.y;
        aR.z += cr * yr.z - ci * yi.z;  aI.z += cr * yi.z + ci * yr.z;
        aR.w += cr * yr.w - ci * yi.w;  aI.w += cr * yi.w + ci * yr.w;
    }
    float4 er = make_float4(fmaxf(aR.x, 0.f), fmaxf(aR.y, 0.f), fmaxf(aR.z, 0.f), fmaxf(aR.w, 0.f));
    float4 ei = make_float4(fmaxf(aI.x, 0.f), fmaxf(aI.y, 0.f), fmaxf(aI.z, 0.f), fmaxf(aI.w, 0.f));
    *(float4*)(out + (size_t)n * 1024 + f) = er;
    *(float4*)(out + (size_t)n * 1024 + FDIM + f) = ei;
}

// ---------------------------------------------------------------------------
// K3: per-feature sum / sumsq of er, ei
// ---------------------------------------------------------------------------
__global__ __launch_bounds__(512) void stats_kernel(
    const float* __restrict__ out, float* __restrict__ sums)
{
    const int tid = threadIdx.x;
    const int r0 = blockIdx.x * 40;
    float sr = 0.f, sr2 = 0.f, si = 0.f, si2 = 0.f;
    for (int r = r0; r < r0 + 40; ++r) {
        const float vr = out[(size_t)r * 1024 + tid];
        const float vi = out[(size_t)r * 1024 + FDIM + tid];
        sr += vr; sr2 = fmaf(vr, vr, sr2);
        si += vi; si2 = fmaf(vi, vi, si2);
    }
    atomicAdd(&sums[tid], sr);
    atomicAdd(&sums[512 + tid], sr2);
    atomicAdd(&sums[1024 + tid], si);
    atomicAdd(&sums[1536 + tid], si2);
}

__global__ __launch_bounds__(512) void bnparams_kernel(
    const float* __restrict__ sums,
    const float* __restrict__ gr, const float* __restrict__ br_,
    const float* __restrict__ gi, const float* __restrict__ bi_,
    float* __restrict__ prm)
{
    const int f = threadIdx.x;
    const float invN = 1.0f / (float)N_NODES;
    const float mur = sums[f] * invN;
    const float varr = fmaf(-mur, mur, sums[512 + f] * invN);
    const float scr = rsqrtf(varr + 1e-5f) * gr[f];
    prm[f] = scr;
    prm[512 + f] = fmaf(-mur, scr, br_[f]);
    const float mui = sums[1024 + f] * invN;
    const float vari = fmaf(-mui, mui, sums[1536 + f] * invN);
    const float sci = rsqrtf(vari + 1e-5f) * gi[f];
    prm[1024 + f] = sci;
    prm[1536 + f] = fmaf(-mui, sci, bi_[f]);
}

__global__ __launch_bounds__(256) void finalize_kernel(
    const float* __restrict__ x, const float* __restrict__ prm,
    float* __restrict__ out)
{
    const int gid = blockIdx.x * 256 + threadIdx.x;
    const int n = gid >> 7;
    const int f = (gid & 127) << 2;
    float4 er = *(const float4*)(out + (size_t)n * 1024 + f);
    float4 ei = *(const float4*)(out + (size_t)n * 1024 + FDIM + f);
    const float4 xv  = *(const float4*)(x + (size_t)n * FDIM + f);
    const float4 scr = *(const float4*)(prm + f);
    const float4 shr = *(const float4*)(prm + 512 + f);
    const float4 sci = *(const float4*)(prm + 1024 + f);
    const float4 shi = *(const float4*)(prm + 1536 + f);
    float4 orr, oii;
    orr.x = fmaf(er.x, scr.x, shr.x) + xv.x;
    orr.y = fmaf(er.y, scr.y, shr.y) + xv.y;
    orr.z = fmaf(er.z, scr.z, shr.z) + xv.z;
    orr.w = fmaf(er.w, scr.w, shr.w) + xv.w;
    oii.x = fmaf(ei.x, sci.x, shi.x);
    oii.y = fmaf(ei.y, sci.y, shi.y);
    oii.z = fmaf(ei.z, sci.z, shi.z);
    oii.w = fmaf(ei.w, sci.w, shi.w);
    *(float4*)(out + (size_t)n * 1024 + f) = orr;
    *(float4*)(out + (size_t)n * 1024 + FDIM + f) = oii;
}

extern "C" void kernel_launch(void* const* d_in, const int* in_sizes, int n_in,
                              void* d_out, int out_size, void* d_ws, size_t ws_size,
                              hipStream_t stream)
{
    const float* x        = (const float*)d_in[0];
    const int* sub_nodes  = (const int*)d_in[2];
    const int* sub_adj    = (const int*)d_in[3];
    const float* Wre      = (const float*)d_in[4];
    const float* Wim      = (const float*)d_in[5];
    const float* bre      = (const float*)d_in[6];
    const float* bim      = (const float*)d_in[7];
    const float* gr       = (const float*)d_in[8];
    const float* br_      = (const float*)d_in[9];
    const float* gi       = (const float*)d_in[10];
    const float* bi_      = (const float*)d_in[11];
    float* out = (float*)d_out;

    // workspace layout
    float* y            = (float*)d_ws;                              // 20000*1024 f32
    unsigned short* xb  = (unsigned short*)(y + (size_t)N_NODES * 1024);   // 20000*512 bf16
    unsigned short* wt  = xb + (size_t)N_NODES * FDIM;               // 1024*512 bf16
    float* sums         = (float*)(wt + (size_t)1024 * FDIM);        // 2048
    float* prm          = sums + 2048;                               // 2048

    hipMemsetAsync(sums, 0, 2048 * sizeof(float), stream);

    conv_x<<<(N_NODES * FDIM) / (256 * 8), 256, 0, stream>>>(x, xb);
    conv_wt<<<dim3(16, 16, 2), dim3(32, 8), 0, stream>>>(Wre, Wim, wt);

    dim3 gg(1024 / BN, (N_NODES + BM - 1) / BM);
    gemm_mfma<<<gg, 256, 0, stream>>>(xb, wt, bre, bim, y);

    evolve_relu<<<N_NODES, 128, 0, stream>>>(y, sub_nodes, sub_adj, out);
    stats_kernel<<<500, 512, 0, stream>>>(out, sums);
    bnparams_kernel<<<1, 512, 0, stream>>>(sums, gr, br_, gi, bi_, prm);
    finalize_kernel<<<(N_NODES * 128) / 256, 256, 0, stream>>>(x, prm, out);
}

// Round 3
// 266.168 us; speedup vs baseline: 1.8809x; 1.1850x over previous
//
#include <hip/hip_runtime.h>

#define N_NODES 20000
#define FDIM 512
#define SSZ 6

typedef __attribute__((ext_vector_type(8))) short bf16x8;
typedef __attribute__((ext_vector_type(4))) float f32x4;
typedef __attribute__((ext_vector_type(8))) unsigned short u16x8;

static __device__ __forceinline__ unsigned short f2bf(float f) {
    unsigned int u = __float_as_uint(f);
    unsigned int r = (u + 0x7fffu + ((u >> 16) & 1u)) >> 16;
    return (unsigned short)r;
}
static __device__ __forceinline__ float bf2f(unsigned short u) {
    return __uint_as_float(((unsigned int)u) << 16);
}

// ---------------------------------------------------------------------------
// K0a: x fp32 -> bf16 (same layout)
// ---------------------------------------------------------------------------
__global__ __launch_bounds__(256) void conv_x(
    const float* __restrict__ x, unsigned short* __restrict__ xb)
{
    const size_t i = ((size_t)blockIdx.x * 256 + threadIdx.x) * 8;
    const float4 a = *(const float4*)(x + i);
    const float4 b = *(const float4*)(x + i + 4);
    u16x8 o;
    o[0] = f2bf(a.x); o[1] = f2bf(a.y); o[2] = f2bf(a.z); o[3] = f2bf(a.w);
    o[4] = f2bf(b.x); o[5] = f2bf(b.y); o[6] = f2bf(b.z); o[7] = f2bf(b.w);
    *(u16x8*)(xb + i) = o;
}

// ---------------------------------------------------------------------------
// K0b: build B^T bf16: wt[n][k] = Wre[k][n] (n<512) | Wim[k][n-512]
// ---------------------------------------------------------------------------
__global__ __launch_bounds__(256) void conv_wt(
    const float* __restrict__ Wre, const float* __restrict__ Wim,
    unsigned short* __restrict__ wt)
{
    __shared__ float tile[32][33];
    const float* W = blockIdx.z ? Wim : Wre;
    const int tx = threadIdx.x, ty = threadIdx.y;
    const int k0 = blockIdx.x * 32;
    const int n0 = blockIdx.y * 32;
#pragma unroll
    for (int i = 0; i < 4; ++i)
        tile[ty + i * 8][tx] = W[(size_t)(k0 + ty + i * 8) * FDIM + n0 + tx];
    __syncthreads();
    unsigned short* wtb = wt + (size_t)blockIdx.z * FDIM * FDIM;
#pragma unroll
    for (int i = 0; i < 4; ++i)
        wtb[(size_t)(n0 + ty + i * 8) * FDIM + k0 + tx] = f2bf(tile[tx][ty + i * 8]);
}

// ---------------------------------------------------------------------------
// K1: bf16 MFMA GEMM.  y[M=20000][1024] = xb[M][512] @ wt^T + bias  (y bf16)
// 128x128 tile, BK=64, 4 waves, 16x16x32 MFMA, global_load_lds w=16,
// XOR chunk swizzle.
// ---------------------------------------------------------------------------
#define BM 128
#define BN 128
#define BK 64

__global__ __launch_bounds__(256) void gemm_mfma(
    const unsigned short* __restrict__ xb,   // [20000][512] bf16
    const unsigned short* __restrict__ wt,   // [1024][512] bf16
    const float* __restrict__ bre, const float* __restrict__ bim,
    unsigned short* __restrict__ y)          // [20000][1024] bf16
{
    __shared__ __align__(16) unsigned short lA[BM * BK];
    __shared__ __align__(16) unsigned short lB[BN * BK];

    const int tid  = threadIdx.x;
    const int wave = tid >> 6;
    const int lane = tid & 63;
    const int rowBase = blockIdx.y * BM;
    const int colBase = blockIdx.x * BN;

    const int wm = (wave >> 1) * 64;
    const int wn = (wave & 1) * 64;

    f32x4 acc[4][4];
#pragma unroll
    for (int i = 0; i < 4; ++i)
#pragma unroll
        for (int j = 0; j < 4; ++j) acc[i][j] = (f32x4){0.f, 0.f, 0.f, 0.f};

    const int srow   = lane >> 3;
    const int schunk = lane & 7;
    const int gchunk = schunk ^ srow;
    const int aRow0  = wave * 32;

    const int fm = lane & 15;
    const int kq = lane >> 4;

    for (int k0 = 0; k0 < FDIM; k0 += BK) {
#pragma unroll
        for (int i = 0; i < 4; ++i) {
            const int trow = aRow0 + i * 8;
            int grow = rowBase + trow + srow;
            if (grow > N_NODES - 1) grow = N_NODES - 1;
            const unsigned short* gp = xb + (size_t)grow * FDIM + k0 + gchunk * 8;
            __builtin_amdgcn_global_load_lds(
                (const __attribute__((address_space(1))) void*)gp,
                (__attribute__((address_space(3))) void*)(lA + trow * BK), 16, 0, 0);
        }
#pragma unroll
        for (int i = 0; i < 4; ++i) {
            const int trow = aRow0 + i * 8;
            const int grow = colBase + trow + srow;
            const unsigned short* gp = wt + (size_t)grow * FDIM + k0 + gchunk * 8;
            __builtin_amdgcn_global_load_lds(
                (const __attribute__((address_space(1))) void*)gp,
                (__attribute__((address_space(3))) void*)(lB + trow * BK), 16, 0, 0);
        }
        __syncthreads();

#pragma unroll
        for (int ks = 0; ks < 2; ++ks) {
            bf16x8 af[4], bfr[4];
            const int g = ks * 4 + kq;
#pragma unroll
            for (int mt = 0; mt < 4; ++mt) {
                const int row = wm + mt * 16 + fm;
                af[mt] = *(const bf16x8*)&lA[row * BK + ((g ^ (row & 7)) << 3)];
            }
#pragma unroll
            for (int nt = 0; nt < 4; ++nt) {
                const int row = wn + nt * 16 + fm;
                bfr[nt] = *(const bf16x8*)&lB[row * BK + ((g ^ (row & 7)) << 3)];
            }
#pragma unroll
            for (int mt = 0; mt < 4; ++mt)
#pragma unroll
                for (int nt = 0; nt < 4; ++nt)
                    acc[mt][nt] = __builtin_amdgcn_mfma_f32_16x16x32_bf16(
                        af[mt], bfr[nt], acc[mt][nt], 0, 0, 0);
        }
        __syncthreads();
    }

    const int rquad = lane >> 4;
#pragma unroll
    for (int nt = 0; nt < 4; ++nt) {
        const int col = colBase + wn + nt * 16 + fm;
        const float bias = (col < FDIM) ? bre[col] : bim[col - FDIM];
#pragma unroll
        for (int mt = 0; mt < 4; ++mt) {
            const int row0 = rowBase + wm + mt * 16 + rquad * 4;
#pragma unroll
            for (int r = 0; r < 4; ++r) {
                const int row = row0 + r;
                if (row < N_NODES)
                    y[(size_t)row * 1024 + col] = f2bf(acc[mt][nt][r] + bias);
            }
        }
    }
}

// ---------------------------------------------------------------------------
// K2: one wave per node. Coeffs computed wave-redundantly (uniform addresses).
// Gather bf16 y (6 nodes x 16 feats/lane), complex combine, ReLU,
// write bf16 er|ei to eb.
// ---------------------------------------------------------------------------
__global__ __launch_bounds__(256) void evolve_relu(
    const unsigned short* __restrict__ y,    // [N][1024] bf16
    const int* __restrict__ sub_nodes,
    const int* __restrict__ sub_adj,
    unsigned short* __restrict__ eb)         // [N][1024] bf16: er|ei
{
    const int wave = threadIdx.x >> 6;
    const int lane = threadIdx.x & 63;
    const int n = blockIdx.x * 4 + wave;

    // --- wave-uniform coefficient computation (broadcast loads) ---
    const int* sa = sub_adj + (size_t)n * (SSZ * SSZ);
    float A[SSZ][SSZ], deg[SSZ];
#pragma unroll
    for (int s = 0; s < SSZ; ++s) {
        float d = 0.f;
#pragma unroll
        for (int t = 0; t < SSZ; ++t) { float a = (float)sa[s * SSZ + t]; A[s][t] = a; d += a; }
        deg[s] = d;
    }
    float p1[SSZ], p2[SSZ], p3[SSZ], p4[SSZ];
#pragma unroll
    for (int t = 0; t < SSZ; ++t) p1[t] = ((t == 0) ? deg[0] : 0.f) - A[0][t];
#pragma unroll
    for (int t = 0; t < SSZ; ++t) {
        float acc = 0.f;
#pragma unroll
        for (int s = 0; s < SSZ; ++s) acc += p1[s] * (((s == t) ? deg[s] : 0.f) - A[s][t]);
        p2[t] = acc;
    }
#pragma unroll
    for (int t = 0; t < SSZ; ++t) {
        float acc = 0.f;
#pragma unroll
        for (int s = 0; s < SSZ; ++s) acc += p2[s] * (((s == t) ? deg[s] : 0.f) - A[s][t]);
        p3[t] = acc;
    }
#pragma unroll
    for (int t = 0; t < SSZ; ++t) {
        float acc = 0.f;
#pragma unroll
        for (int s = 0; s < SSZ; ++s) acc += p3[s] * (((s == t) ? deg[s] : 0.f) - A[s][t]);
        p4[t] = acc;
    }
    float rre[SSZ], rim[SSZ];
#pragma unroll
    for (int t = 0; t < SSZ; ++t) {
        rre[t] = ((t == 0) ? 1.f : 0.f) - 3.125e-4f * p2[t] + 1.6276041666666668e-8f * p4[t];
        rim[t] = -0.025f * p1[t] + 2.6041666666666666e-6f * p3[t];
    }

    // --- gather + combine: lane owns features [f, f+8) for re and im ---
    const int f = lane << 3;
    float aR[8] = {0.f}, aI[8] = {0.f};
#pragma unroll
    for (int s = 0; s < SSZ; ++s) {
        const int nd = sub_nodes[n * SSZ + s];
        const float cr = rre[s], ci = rim[s];
        const unsigned short* base = y + (size_t)nd * 1024 + f;
        const u16x8 yr8 = *(const u16x8*)base;
        const u16x8 yi8 = *(const u16x8*)(base + FDIM);
#pragma unroll
        for (int j = 0; j < 8; ++j) {
            const float yr = bf2f(yr8[j]);
            const float yi = bf2f(yi8[j]);
            aR[j] = fmaf(cr, yr, fmaf(-ci, yi, aR[j]));
            aI[j] = fmaf(cr, yi, fmaf(ci, yr, aI[j]));
        }
    }
    u16x8 er8, ei8;
#pragma unroll
    for (int j = 0; j < 8; ++j) {
        er8[j] = f2bf(fmaxf(aR[j], 0.f));
        ei8[j] = f2bf(fmaxf(aI[j], 0.f));
    }
    *(u16x8*)(eb + (size_t)n * 1024 + f) = er8;
    *(u16x8*)(eb + (size_t)n * 1024 + FDIM + f) = ei8;
}

// ---------------------------------------------------------------------------
// K3: per-feature sum / sumsq of er, ei from bf16 eb
// ---------------------------------------------------------------------------
__global__ __launch_bounds__(512) void stats_kernel(
    const unsigned short* __restrict__ eb, float* __restrict__ sums)
{
    const int tid = threadIdx.x;
    const int r0 = blockIdx.x * 40;
    float sr = 0.f, sr2 = 0.f, si = 0.f, si2 = 0.f;
    for (int r = r0; r < r0 + 40; ++r) {
        const float vr = bf2f(eb[(size_t)r * 1024 + tid]);
        const float vi = bf2f(eb[(size_t)r * 1024 + FDIM + tid]);
        sr += vr; sr2 = fmaf(vr, vr, sr2);
        si += vi; si2 = fmaf(vi, vi, si2);
    }
    atomicAdd(&sums[tid], sr);
    atomicAdd(&sums[512 + tid], sr2);
    atomicAdd(&sums[1024 + tid], si);
    atomicAdd(&sums[1536 + tid], si2);
}

__global__ __launch_bounds__(512) void bnparams_kernel(
    const float* __restrict__ sums,
    const float* __restrict__ gr, const float* __restrict__ br_,
    const float* __restrict__ gi, const float* __restrict__ bi_,
    float* __restrict__ prm)
{
    const int f = threadIdx.x;
    const float invN = 1.0f / (float)N_NODES;
    const float mur = sums[f] * invN;
    const float varr = fmaf(-mur, mur, sums[512 + f] * invN);
    const float scr = rsqrtf(varr + 1e-5f) * gr[f];
    prm[f] = scr;
    prm[512 + f] = fmaf(-mur, scr, br_[f]);
    const float mui = sums[1024 + f] * invN;
    const float vari = fmaf(-mui, mui, sums[1536 + f] * invN);
    const float sci = rsqrtf(vari + 1e-5f) * gi[f];
    prm[1024 + f] = sci;
    prm[1536 + f] = fmaf(-mui, sci, bi_[f]);
}

// ---------------------------------------------------------------------------
// K4: BN apply + residual; reads bf16 eb + fp32 x, writes fp32 out
// ---------------------------------------------------------------------------
__global__ __launch_bounds__(256) void finalize_kernel(
    const float* __restrict__ x, const unsigned short* __restrict__ eb,
    const float* __restrict__ prm, float* __restrict__ out)
{
    const int gid = blockIdx.x * 256 + threadIdx.x;    // N*64 threads
    const int n = gid >> 6;
    const int f = (gid & 63) << 3;
    const u16x8 er8 = *(const u16x8*)(eb + (size_t)n * 1024 + f);
    const u16x8 ei8 = *(const u16x8*)(eb + (size_t)n * 1024 + FDIM + f);
    float orr[8], oii[8];
#pragma unroll
    for (int j = 0; j < 8; ++j) {
        const float scr = prm[f + j],        shr = prm[512 + f + j];
        const float sci = prm[1024 + f + j], shi = prm[1536 + f + j];
        const float xv = x[(size_t)n * FDIM + f + j];
        orr[j] = fmaf(bf2f(er8[j]), scr, shr) + xv;
        oii[j] = fmaf(bf2f(ei8[j]), sci, shi);
    }
#pragma unroll
    for (int j = 0; j < 8; j += 4) {
        *(float4*)(out + (size_t)n * 1024 + f + j) =
            make_float4(orr[j], orr[j + 1], orr[j + 2], orr[j + 3]);
        *(float4*)(out + (size_t)n * 1024 + FDIM + f + j) =
            make_float4(oii[j], oii[j + 1], oii[j + 2], oii[j + 3]);
    }
}

extern "C" void kernel_launch(void* const* d_in, const int* in_sizes, int n_in,
                              void* d_out, int out_size, void* d_ws, size_t ws_size,
                              hipStream_t stream)
{
    const float* x        = (const float*)d_in[0];
    const int* sub_nodes  = (const int*)d_in[2];
    const int* sub_adj    = (const int*)d_in[3];
    const float* Wre      = (const float*)d_in[4];
    const float* Wim      = (const float*)d_in[5];
    const float* bre      = (const float*)d_in[6];
    const float* bim      = (const float*)d_in[7];
    const float* gr       = (const float*)d_in[8];
    const float* br_      = (const float*)d_in[9];
    const float* gi       = (const float*)d_in[10];
    const float* bi_      = (const float*)d_in[11];
    float* out = (float*)d_out;

    // workspace layout (all bf16 intermediates)
    unsigned short* y  = (unsigned short*)d_ws;                     // N*1024 bf16
    unsigned short* eb = y + (size_t)N_NODES * 1024;                // N*1024 bf16
    unsigned short* xb = eb + (size_t)N_NODES * 1024;               // N*512  bf16
    unsigned short* wt = xb + (size_t)N_NODES * FDIM;               // 1024*512 bf16
    float* sums        = (float*)(wt + (size_t)1024 * FDIM);        // 2048
    float* prm         = sums + 2048;                               // 2048

    hipMemsetAsync(sums, 0, 2048 * sizeof(float), stream);

    conv_x<<<(N_NODES * FDIM) / (256 * 8), 256, 0, stream>>>(x, xb);
    conv_wt<<<dim3(16, 16, 2), dim3(32, 8), 0, stream>>>(Wre, Wim, wt);

    dim3 gg(1024 / BN, (N_NODES + BM - 1) / BM);
    gemm_mfma<<<gg, 256, 0, stream>>>(xb, wt, bre, bim, y);

    evolve_relu<<<N_NODES / 4, 256, 0, stream>>>(y, sub_nodes, sub_adj, eb);
    stats_kernel<<<500, 512, 0, stream>>>(eb, sums);
    bnparams_kernel<<<1, 512, 0, stream>>>(sums, gr, br_, gi, bi_, prm);
    finalize_kernel<<<(N_NODES * 64) / 256, 256, 0, stream>>>(x, eb, prm, out);
}

// Round 4
// 248.772 us; speedup vs baseline: 2.0124x; 1.0699x over previous
//
#include <hip/hip_runtime.h>

#define N_NODES 20000
#define FDIM 512
#define SSZ 6

typedef __attribute__((ext_vector_type(8))) short bf16x8;
typedef __attribute__((ext_vector_type(4))) float f32x4;
typedef __attribute__((ext_vector_type(8))) unsigned short u16x8;

static __device__ __forceinline__ unsigned short f2bf(float f) {
    unsigned int u = __float_as_uint(f);
    unsigned int r = (u + 0x7fffu + ((u >> 16) & 1u)) >> 16;
    return (unsigned short)r;
}
static __device__ __forceinline__ float bf2f(unsigned short u) {
    return __uint_as_float(((unsigned int)u) << 16);
}

// ---------------------------------------------------------------------------
// K0: fused prep. blocks [0,5000): x->bf16. blocks [5000,5512): W^T bf16.
// block 5512: zero sums[2048].
// ---------------------------------------------------------------------------
__global__ __launch_bounds__(256) void conv_all(
    const float* __restrict__ x, const float* __restrict__ Wre,
    const float* __restrict__ Wim, unsigned short* __restrict__ xb,
    unsigned short* __restrict__ wt, float* __restrict__ sums)
{
    const int blk = blockIdx.x;
    const int tid = threadIdx.x;
    if (blk < 5000) {
        const size_t i = ((size_t)blk * 256 + tid) * 8;
        const float4 a = *(const float4*)(x + i);
        const float4 b = *(const float4*)(x + i + 4);
        u16x8 o;
        o[0] = f2bf(a.x); o[1] = f2bf(a.y); o[2] = f2bf(a.z); o[3] = f2bf(a.w);
        o[4] = f2bf(b.x); o[5] = f2bf(b.y); o[6] = f2bf(b.z); o[7] = f2bf(b.w);
        *(u16x8*)(xb + i) = o;
    } else if (blk < 5512) {
        __shared__ float tile[32][33];
        const int bidx = blk - 5000;
        const int z = bidx >> 8;              // 0:re 1:im
        const int rem = bidx & 255;
        const int k0 = (rem & 15) * 32;
        const int n0 = (rem >> 4) * 32;
        const float* W = z ? Wim : Wre;
        const int tx = tid & 31, ty = tid >> 5;
#pragma unroll
        for (int i = 0; i < 4; ++i)
            tile[ty + i * 8][tx] = W[(size_t)(k0 + ty + i * 8) * FDIM + n0 + tx];
        __syncthreads();
        unsigned short* wtb = wt + (size_t)z * FDIM * FDIM;
#pragma unroll
        for (int i = 0; i < 4; ++i)
            wtb[(size_t)(n0 + ty + i * 8) * FDIM + k0 + tx] = f2bf(tile[tx][ty + i * 8]);
    } else {
#pragma unroll
        for (int i = 0; i < 8; ++i) sums[i * 256 + tid] = 0.f;
    }
}

// ---------------------------------------------------------------------------
// K1: bf16 MFMA GEMM.  y[20000][1024] = xb @ wt^T + bias (bf16 out)
// 64x128 tile, BK=64, 4 waves (2x2, wave tile 32x64), 2x4 frags 16x16x32.
// global_load_lds w=16 staging, XOR chunk swizzle.
// ---------------------------------------------------------------------------
#define BM 64
#define BN 128
#define BK 64

__global__ __launch_bounds__(256) void gemm_mfma(
    const unsigned short* __restrict__ xb,   // [20000][512]
    const unsigned short* __restrict__ wt,   // [1024][512]
    const float* __restrict__ bre, const float* __restrict__ bim,
    unsigned short* __restrict__ y)          // [20000][1024]
{
    __shared__ __align__(16) unsigned short lA[BM * BK];   // 8 KB
    __shared__ __align__(16) unsigned short lB[BN * BK];   // 16 KB

    const int tid  = threadIdx.x;
    const int wave = tid >> 6;
    const int lane = tid & 63;
    const int rowBase = blockIdx.y * BM;
    const int colBase = blockIdx.x * BN;

    const int wm = (wave >> 1) * 32;
    const int wn = (wave & 1) * 64;

    f32x4 acc[2][4];
#pragma unroll
    for (int i = 0; i < 2; ++i)
#pragma unroll
        for (int j = 0; j < 4; ++j) acc[i][j] = (f32x4){0.f, 0.f, 0.f, 0.f};

    const int srow   = lane >> 3;
    const int schunk = lane & 7;
    const int gchunk = schunk ^ srow;

    const int fm = lane & 15;
    const int kq = lane >> 4;

    for (int k0 = 0; k0 < FDIM; k0 += BK) {
        // stage A: wave stages rows [wave*16, wave*16+16)
#pragma unroll
        for (int i = 0; i < 2; ++i) {
            const int trow = wave * 16 + i * 8;
            int grow = rowBase + trow + srow;
            if (grow > N_NODES - 1) grow = N_NODES - 1;
            const unsigned short* gp = xb + (size_t)grow * FDIM + k0 + gchunk * 8;
            __builtin_amdgcn_global_load_lds(
                (const __attribute__((address_space(1))) void*)gp,
                (__attribute__((address_space(3))) void*)(lA + trow * BK), 16, 0, 0);
        }
        // stage B: wave stages rows [wave*32, wave*32+32)
#pragma unroll
        for (int i = 0; i < 4; ++i) {
            const int trow = wave * 32 + i * 8;
            const int grow = colBase + trow + srow;
            const unsigned short* gp = wt + (size_t)grow * FDIM + k0 + gchunk * 8;
            __builtin_amdgcn_global_load_lds(
                (const __attribute__((address_space(1))) void*)gp,
                (__attribute__((address_space(3))) void*)(lB + trow * BK), 16, 0, 0);
        }
        __syncthreads();

#pragma unroll
        for (int ks = 0; ks < 2; ++ks) {
            bf16x8 af[2], bfr[4];
            const int g = ks * 4 + kq;
#pragma unroll
            for (int mt = 0; mt < 2; ++mt) {
                const int row = wm + mt * 16 + fm;
                af[mt] = *(const bf16x8*)&lA[row * BK + ((g ^ (row & 7)) << 3)];
            }
#pragma unroll
            for (int nt = 0; nt < 4; ++nt) {
                const int row = wn + nt * 16 + fm;
                bfr[nt] = *(const bf16x8*)&lB[row * BK + ((g ^ (row & 7)) << 3)];
            }
#pragma unroll
            for (int mt = 0; mt < 2; ++mt)
#pragma unroll
                for (int nt = 0; nt < 4; ++nt)
                    acc[mt][nt] = __builtin_amdgcn_mfma_f32_16x16x32_bf16(
                        af[mt], bfr[nt], acc[mt][nt], 0, 0, 0);
        }
        __syncthreads();
    }

    const int rquad = lane >> 4;
#pragma unroll
    for (int nt = 0; nt < 4; ++nt) {
        const int col = colBase + wn + nt * 16 + fm;
        const float bias = (col < FDIM) ? bre[col] : bim[col - FDIM];
#pragma unroll
        for (int mt = 0; mt < 2; ++mt) {
            const int row0 = rowBase + wm + mt * 16 + rquad * 4;
#pragma unroll
            for (int r = 0; r < 4; ++r) {
                const int row = row0 + r;
                if (row < N_NODES)
                    y[(size_t)row * 1024 + col] = f2bf(acc[mt][nt][r] + bias);
            }
        }
    }
}

// ---------------------------------------------------------------------------
// K2: evolve + ReLU + fused BN stats. Block = 16 nodes (4 waves x 4 nodes).
// Per-wave register partial sums -> LDS cross-wave reduce -> 2048 atomics/blk.
// ---------------------------------------------------------------------------
__global__ __launch_bounds__(256) void evolve_stats(
    const unsigned short* __restrict__ y,
    const int* __restrict__ sub_nodes,
    const int* __restrict__ sub_adj,
    unsigned short* __restrict__ eb,
    float* __restrict__ sums)
{
    __shared__ float lsum[2048];
    const int wave = threadIdx.x >> 6;
    const int lane = threadIdx.x & 63;
    const int f = lane << 3;

    float sR[8] = {0.f}, sR2[8] = {0.f}, sI[8] = {0.f}, sI2[8] = {0.f};

    for (int q = 0; q < 4; ++q) {
        const int n = blockIdx.x * 16 + wave * 4 + q;

        // wave-uniform coefficient computation
        const int* sa = sub_adj + (size_t)n * (SSZ * SSZ);
        float A[SSZ][SSZ], deg[SSZ];
#pragma unroll
        for (int s = 0; s < SSZ; ++s) {
            float d = 0.f;
#pragma unroll
            for (int t = 0; t < SSZ; ++t) { float a = (float)sa[s * SSZ + t]; A[s][t] = a; d += a; }
            deg[s] = d;
        }
        float p1[SSZ], p2[SSZ], p3[SSZ], p4[SSZ];
#pragma unroll
        for (int t = 0; t < SSZ; ++t) p1[t] = ((t == 0) ? deg[0] : 0.f) - A[0][t];
#pragma unroll
        for (int t = 0; t < SSZ; ++t) {
            float acc = 0.f;
#pragma unroll
            for (int s = 0; s < SSZ; ++s) acc += p1[s] * (((s == t) ? deg[s] : 0.f) - A[s][t]);
            p2[t] = acc;
        }
#pragma unroll
        for (int t = 0; t < SSZ; ++t) {
            float acc = 0.f;
#pragma unroll
            for (int s = 0; s < SSZ; ++s) acc += p2[s] * (((s == t) ? deg[s] : 0.f) - A[s][t]);
            p3[t] = acc;
        }
#pragma unroll
        for (int t = 0; t < SSZ; ++t) {
            float acc = 0.f;
#pragma unroll
            for (int s = 0; s < SSZ; ++s) acc += p3[s] * (((s == t) ? deg[s] : 0.f) - A[s][t]);
            p4[t] = acc;
        }
        float rre[SSZ], rim[SSZ];
#pragma unroll
        for (int t = 0; t < SSZ; ++t) {
            rre[t] = ((t == 0) ? 1.f : 0.f) - 3.125e-4f * p2[t] + 1.6276041666666668e-8f * p4[t];
            rim[t] = -0.025f * p1[t] + 2.6041666666666666e-6f * p3[t];
        }

        // gather + complex combine
        float aR[8] = {0.f}, aI[8] = {0.f};
#pragma unroll
        for (int s = 0; s < SSZ; ++s) {
            const int nd = sub_nodes[n * SSZ + s];
            const float cr = rre[s], ci = rim[s];
            const unsigned short* base = y + (size_t)nd * 1024 + f;
            const u16x8 yr8 = *(const u16x8*)base;
            const u16x8 yi8 = *(const u16x8*)(base + FDIM);
#pragma unroll
            for (int j = 0; j < 8; ++j) {
                const float yr = bf2f(yr8[j]);
                const float yi = bf2f(yi8[j]);
                aR[j] = fmaf(cr, yr, fmaf(-ci, yi, aR[j]));
                aI[j] = fmaf(cr, yi, fmaf(ci, yr, aI[j]));
            }
        }
        u16x8 er8, ei8;
#pragma unroll
        for (int j = 0; j < 8; ++j) {
            const unsigned short re = f2bf(fmaxf(aR[j], 0.f));
            const unsigned short im = f2bf(fmaxf(aI[j], 0.f));
            er8[j] = re; ei8[j] = im;
            const float erv = bf2f(re), eiv = bf2f(im);
            sR[j] += erv;  sR2[j] = fmaf(erv, erv, sR2[j]);
            sI[j] += eiv;  sI2[j] = fmaf(eiv, eiv, sI2[j]);
        }
        *(u16x8*)(eb + (size_t)n * 1024 + f) = er8;
        *(u16x8*)(eb + (size_t)n * 1024 + FDIM + f) = ei8;
    }

    // cross-wave reduce in LDS (sequential waves, no atomics)
    if (wave == 0) {
#pragma unroll
        for (int j = 0; j < 8; ++j) {
            lsum[f + j] = sR[j];  lsum[512 + f + j] = sR2[j];
            lsum[1024 + f + j] = sI[j];  lsum[1536 + f + j] = sI2[j];
        }
    }
    for (int w = 1; w < 4; ++w) {
        __syncthreads();
        if (wave == w) {
#pragma unroll
            for (int j = 0; j < 8; ++j) {
                lsum[f + j] += sR[j];  lsum[512 + f + j] += sR2[j];
                lsum[1024 + f + j] += sI[j];  lsum[1536 + f + j] += sI2[j];
            }
        }
    }
    __syncthreads();
#pragma unroll
    for (int i = 0; i < 8; ++i) {
        const int idx = i * 256 + threadIdx.x;
        atomicAdd(&sums[idx], lsum[idx]);
    }
}

// ---------------------------------------------------------------------------
// K3: finalize. Per-thread BN params from sums (register, float4 loads),
// apply + residual, write fp32 out.
// ---------------------------------------------------------------------------
__global__ __launch_bounds__(256) void finalize_kernel(
    const float* __restrict__ x, const unsigned short* __restrict__ eb,
    const float* __restrict__ sums,
    const float* __restrict__ gr, const float* __restrict__ br_,
    const float* __restrict__ gi, const float* __restrict__ bi_,
    float* __restrict__ out)
{
    const int gid = blockIdx.x * 256 + threadIdx.x;    // N*64 threads
    const int n = gid >> 6;
    const int f = (gid & 63) << 3;
    const float invN = 1.0f / (float)N_NODES;

    float scr[8], shr[8], sci[8], shi[8];
#pragma unroll
    for (int h = 0; h < 2; ++h) {
        const int fo = f + h * 4;
        const float4 s1 = *(const float4*)(sums + fo);
        const float4 s2 = *(const float4*)(sums + 512 + fo);
        const float4 s3 = *(const float4*)(sums + 1024 + fo);
        const float4 s4 = *(const float4*)(sums + 1536 + fo);
        const float4 g1 = *(const float4*)(gr + fo);
        const float4 b1 = *(const float4*)(br_ + fo);
        const float4 g2 = *(const float4*)(gi + fo);
        const float4 b2 = *(const float4*)(bi_ + fo);
        const float mu[4] = {s1.x * invN, s1.y * invN, s1.z * invN, s1.w * invN};
        const float q2[4] = {s2.x * invN, s2.y * invN, s2.z * invN, s2.w * invN};
        const float mi[4] = {s3.x * invN, s3.y * invN, s3.z * invN, s3.w * invN};
        const float qi[4] = {s4.x * invN, s4.y * invN, s4.z * invN, s4.w * invN};
        const float gg1[4] = {g1.x, g1.y, g1.z, g1.w};
        const float bb1[4] = {b1.x, b1.y, b1.z, b1.w};
        const float gg2[4] = {g2.x, g2.y, g2.z, g2.w};
        const float bb2[4] = {b2.x, b2.y, b2.z, b2.w};
#pragma unroll
        for (int j = 0; j < 4; ++j) {
            const float vr = fmaf(-mu[j], mu[j], q2[j]);
            const float sc1 = rsqrtf(vr + 1e-5f) * gg1[j];
            scr[h * 4 + j] = sc1;
            shr[h * 4 + j] = fmaf(-mu[j], sc1, bb1[j]);
            const float vi = fmaf(-mi[j], mi[j], qi[j]);
            const float sc2 = rsqrtf(vi + 1e-5f) * gg2[j];
            sci[h * 4 + j] = sc2;
            shi[h * 4 + j] = fmaf(-mi[j], sc2, bb2[j]);
        }
    }

    const u16x8 er8 = *(const u16x8*)(eb + (size_t)n * 1024 + f);
    const u16x8 ei8 = *(const u16x8*)(eb + (size_t)n * 1024 + FDIM + f);
    float orr[8], oii[8];
#pragma unroll
    for (int j = 0; j < 8; ++j) {
        const float xv = x[(size_t)n * FDIM + f + j];
        orr[j] = fmaf(bf2f(er8[j]), scr[j], shr[j]) + xv;
        oii[j] = fmaf(bf2f(ei8[j]), sci[j], shi[j]);
    }
#pragma unroll
    for (int j = 0; j < 8; j += 4) {
        *(float4*)(out + (size_t)n * 1024 + f + j) =
            make_float4(orr[j], orr[j + 1], orr[j + 2], orr[j + 3]);
        *(float4*)(out + (size_t)n * 1024 + FDIM + f + j) =
            make_float4(oii[j], oii[j + 1], oii[j + 2], oii[j + 3]);
    }
}

extern "C" void kernel_launch(void* const* d_in, const int* in_sizes, int n_in,
                              void* d_out, int out_size, void* d_ws, size_t ws_size,
                              hipStream_t stream)
{
    const float* x        = (const float*)d_in[0];
    const int* sub_nodes  = (const int*)d_in[2];
    const int* sub_adj    = (const int*)d_in[3];
    const float* Wre      = (const float*)d_in[4];
    const float* Wim      = (const float*)d_in[5];
    const float* bre      = (const float*)d_in[6];
    const float* bim      = (const float*)d_in[7];
    const float* gr       = (const float*)d_in[8];
    const float* br_      = (const float*)d_in[9];
    const float* gi       = (const float*)d_in[10];
    const float* bi_      = (const float*)d_in[11];
    float* out = (float*)d_out;

    unsigned short* y  = (unsigned short*)d_ws;                     // N*1024 bf16
    unsigned short* eb = y + (size_t)N_NODES * 1024;                // N*1024 bf16
    unsigned short* xb = eb + (size_t)N_NODES * 1024;               // N*512  bf16
    unsigned short* wt = xb + (size_t)N_NODES * FDIM;               // 1024*512 bf16
    float* sums        = (float*)(wt + (size_t)1024 * FDIM);        // 2048

    conv_all<<<5513, 256, 0, stream>>>(x, Wre, Wim, xb, wt, sums);

    dim3 gg(1024 / BN, (N_NODES + BM - 1) / BM);
    gemm_mfma<<<gg, 256, 0, stream>>>(xb, wt, bre, bim, y);

    evolve_stats<<<N_NODES / 16, 256, 0, stream>>>(y, sub_nodes, sub_adj, eb, sums);

    finalize_kernel<<<(N_NODES * 64) / 256, 256, 0, stream>>>(
        x, eb, sums, gr, br_, gi, bi_, out);
}